// Round 1
// baseline (42.891 us; speedup 1.0000x reference)
//
#include <hip/hip_runtime.h>

// Problem constants (from reference setup_inputs)
constexpr int Bn = 256;
constexpr int Nn = 16384;
constexpr int Hh = 96;
constexpr int Ww = 96;

constexpr int THREADS = 512;
constexpr int CHUNKS  = 2;          // blocks per batch
constexpr int PS  = 100;            // padded stride (2-pad each side)
constexpr int PSZ = PS * PS;        // 10000 floats per padded map

// Main kernel: one block handles one (batch, chunk) pair.
// Stages edge+mask maps zero-padded into LDS, then processes corners.
__global__ __launch_bounds__(THREADS, 2)
void geo_kernel(const float* __restrict__ corners,
                const float* __restrict__ edge,
                const float* __restrict__ mask,
                double* __restrict__ acc)
{
    __shared__ float sE[PSZ];
    __shared__ float sM[PSZ];
    __shared__ float redE[THREADS / 64];
    __shared__ float redM[THREADS / 64];

    const int b     = blockIdx.x >> 1;   // CHUNKS == 2
    const int chunk = blockIdx.x & 1;

    // --- stage: zero whole padded buffers (float4), then copy interior ---
    {
        const float4 z4 = make_float4(0.f, 0.f, 0.f, 0.f);
        float4* sE4 = (float4*)sE;
        float4* sM4 = (float4*)sM;
        for (int i = threadIdx.x; i < PSZ / 4; i += THREADS) {
            sE4[i] = z4;
            sM4[i] = z4;
        }
    }
    __syncthreads();
    {
        const float2* eg = (const float2*)(edge + (size_t)b * Hh * Ww);
        const float2* mg = (const float2*)(mask + (size_t)b * Hh * Ww);
        for (int i = threadIdx.x; i < Hh * Ww / 2; i += THREADS) {
            int row  = i / (Ww / 2);
            int col2 = i - row * (Ww / 2);
            int dst  = (row + 2) * PS + 2 + col2 * 2;
            *(float2*)&sE[dst] = eg[i];
            *(float2*)&sM[dst] = mg[i];
        }
    }
    __syncthreads();

    // --- per-corner work ---
    float eAcc = 0.f, mAcc = 0.f;
    const int per_block = Nn / CHUNKS;                      // 8192
    const float2* c2 =
        (const float2*)(corners + (size_t)b * Nn * 2) + (size_t)chunk * per_block;

    for (int i = threadIdx.x; i < per_block; i += THREADS) {
        float2 c = c2[i];
        // ix = ((gx+1)*W - 1)*0.5 with gx = 2*cx - 1  ==>  ix = 96*cx - 0.5
        float ix = fmaf(c.x, 96.f, -0.5f);
        float iy = fmaf(c.y, 96.f, -0.5f);
        float x0f = floorf(ix), y0f = floorf(iy);
        float wx = ix - x0f, wy = iy - y0f;
        int x0 = (int)x0f, y0 = (int)y0f;

        // edge: 4x4 patch at rows y0-1..y0+2, cols x0-1..x0+2
        // padded addr of pixel (x,y) is (y+2)*PS + (x+2)
        int eb = (y0 + 1) * PS + (x0 + 1);
        float hh[4][3];
#pragma unroll
        for (int pr = 0; pr < 4; ++pr) {
            int base = eb + pr * PS;
            float p0 = sE[base + 0];
            float p1 = sE[base + 1];
            float p2 = sE[base + 2];
            float p3 = sE[base + 3];
            hh[pr][0] = fmaf(wx, p1 - p0, p0);
            hh[pr][1] = fmaf(wx, p2 - p1, p1);
            hh[pr][2] = fmaf(wx, p3 - p2, p2);
        }
        float best = 0.f;
#pragma unroll
        for (int j = 0; j < 3; ++j) {
#pragma unroll
            for (int k = 0; k < 3; ++k) {
                float s = fmaf(wy, hh[j + 1][k] - hh[j][k], hh[j][k]);
                best = (j == 0 && k == 0) ? s : fmaxf(best, s);
            }
        }
        eAcc += best;

        // mask: 2x2 at (x0..x0+1, y0..y0+1)
        int mb = (y0 + 2) * PS + (x0 + 2);
        float q0 = sM[mb];
        float q1 = sM[mb + 1];
        float q2 = sM[mb + PS];
        float q3 = sM[mb + PS + 1];
        float t = fmaf(wx, q1 - q0, q0);
        float u = fmaf(wx, q3 - q2, q2);
        float m = fmaf(wy, u - t, t);
        float d = m - 0.5f;
        mAcc = fmaf(d, d, mAcc);
    }

    // --- reduce: wave shuffle, then cross-wave via LDS, one atomic per block ---
#pragma unroll
    for (int off = 32; off > 0; off >>= 1) {
        eAcc += __shfl_xor(eAcc, off);
        mAcc += __shfl_xor(mAcc, off);
    }
    const int wv = threadIdx.x >> 6;
    const int ln = threadIdx.x & 63;
    if (ln == 0) { redE[wv] = eAcc; redM[wv] = mAcc; }
    __syncthreads();
    if (threadIdx.x == 0) {
        float e = 0.f, m = 0.f;
#pragma unroll
        for (int w = 0; w < THREADS / 64; ++w) { e += redE[w]; m += redM[w]; }
        atomicAdd(&acc[0], (double)e);
        atomicAdd(&acc[1], (double)m);
    }
}

__global__ void geo_finalize(const double* __restrict__ acc, float* __restrict__ out)
{
    const double inv = 1.0 / (double)((long long)Bn * (long long)Nn);
    double edge_loss = 1.0 - acc[0] * inv;   // mean(1 - best) = 1 - mean(best)
    double mask_loss = acc[1] * inv;
    out[0] = (float)(edge_loss + 2.0 * mask_loss);
}

extern "C" void kernel_launch(void* const* d_in, const int* in_sizes, int n_in,
                              void* d_out, int out_size, void* d_ws, size_t ws_size,
                              hipStream_t stream)
{
    const float* corners = (const float*)d_in[0];
    const float* edge    = (const float*)d_in[1];
    const float* mask    = (const float*)d_in[2];
    float* out  = (float*)d_out;
    double* acc = (double*)d_ws;

    hipMemsetAsync(acc, 0, 2 * sizeof(double), stream);
    geo_kernel<<<Bn * CHUNKS, THREADS, 0, stream>>>(corners, edge, mask, acc);
    geo_finalize<<<1, 1, 0, stream>>>(acc, out);
}

// Round 2
// 39.912 us; speedup vs baseline: 1.0746x; 1.0746x over previous
//
#include <hip/hip_runtime.h>

// Problem constants (from reference setup_inputs)
constexpr int Bn = 256;
constexpr int Nn = 16384;
constexpr int Hh = 96;
constexpr int Ww = 96;

constexpr int THREADS = 1024;
constexpr int PS2  = 100;           // float2 entries per padded row
constexpr int ROWS = 100;           // padded rows
constexpr int ENT  = ROWS * PS2;    // 10000 float2 entries per map

// Duplicated-pair layout: entry (py,px) = (P[py-2][px-2], P[py-2][px-1]),
// zero outside the 96x96 interior. Every bilinear gather becomes an
// aligned ds_read_b64 fetching two horizontally-adjacent pixels.
__global__ __launch_bounds__(THREADS, 1)
void geo_kernel(const float* __restrict__ corners,
                const float* __restrict__ edge,
                const float* __restrict__ mask,
                double* __restrict__ acc,      // [0]=edge sum, [1]=mask sum, [2]=counter
                float* __restrict__ out)
{
    __shared__ float2 sE[ENT];
    __shared__ float2 sM[ENT];
    __shared__ float redE[THREADS / 64];
    __shared__ float redM[THREADS / 64];

    const int b = blockIdx.x;

    // --- zero both padded buffers (float4 = 2 entries at a time) ---
    {
        const float4 z4 = make_float4(0.f, 0.f, 0.f, 0.f);
        float4* e4 = (float4*)sE;
        float4* m4 = (float4*)sM;
        for (int i = threadIdx.x; i < ENT / 2; i += THREADS) {
            e4[i] = z4;
            m4[i] = z4;
        }
    }
    __syncthreads();

    // --- fill interior with duplicated pairs ---
    // thread handles image cols (2j, 2j+1) of row r: one b64 + two b32 writes.
    {
        const float2* eg = (const float2*)(edge + (size_t)b * Hh * Ww);
        const float2* mg = (const float2*)(mask + (size_t)b * Hh * Ww);
        for (int i = threadIdx.x; i < (Ww / 2) * Hh; i += THREADS) {
            int r = i / (Ww / 2);
            int j = i - r * (Ww / 2);
            int row = (r + 2) * PS2;
            float2 ve = eg[i];
            sE[row + 2 * j + 2]   = ve;     // even entry (I[2j], I[2j+1])
            sE[row + 2 * j + 1].y = ve.x;   // odd-left  .y = I[2j]
            sE[row + 2 * j + 3].x = ve.y;   // odd-right .x = I[2j+1]
            float2 vm = mg[i];
            sM[row + 2 * j + 2]   = vm;
            sM[row + 2 * j + 1].y = vm.x;
            sM[row + 2 * j + 3].x = vm.y;
        }
    }
    __syncthreads();

    // --- per-corner work ---
    float eAcc = 0.f, mAcc = 0.f;
    const float2* c2 = (const float2*)(corners + (size_t)b * Nn * 2);

    for (int i = threadIdx.x; i < Nn; i += THREADS) {
        float2 c = c2[i];
        // ix = ((gx+1)*W - 1)*0.5 with gx = 2*cx - 1  ==>  ix = 96*cx - 0.5
        float ix = fmaf(c.x, 96.f, -0.5f);
        float iy = fmaf(c.y, 96.f, -0.5f);
        float x0f = floorf(ix), y0f = floorf(iy);
        float wx = ix - x0f, wy = iy - y0f;
        int x0 = (int)x0f, y0 = (int)y0f;

        // edge: 4x4 patch rows y0-1..y0+2, cols x0-1..x0+2
        // padded float2 base index: row (y0+1+pr), col (x0+1) and (x0+3)
        int cb = (y0 + 1) * PS2 + (x0 + 1);
        float h[4][3];
#pragma unroll
        for (int pr = 0; pr < 4; ++pr) {
            float2 a = sE[cb + pr * PS2];       // (p0, p1)
            float2 d = sE[cb + pr * PS2 + 2];   // (p2, p3)
            h[pr][0] = fmaf(wx, a.y - a.x, a.x);
            h[pr][1] = fmaf(wx, d.x - a.y, a.y);
            h[pr][2] = fmaf(wx, d.y - d.x, d.x);
        }
        float best = 0.f;
#pragma unroll
        for (int j = 0; j < 3; ++j) {
#pragma unroll
            for (int k = 0; k < 3; ++k) {
                float s = fmaf(wy, h[j + 1][k] - h[j][k], h[j][k]);
                best = (j == 0 && k == 0) ? s : fmaxf(best, s);
            }
        }
        eAcc += best;

        // mask: 2x2 at (x0..x0+1, y0..y0+1) -> two b64 reads
        int mb = (y0 + 2) * PS2 + (x0 + 2);
        float2 m0 = sM[mb];
        float2 m1 = sM[mb + PS2];
        float t = fmaf(wx, m0.y - m0.x, m0.x);
        float u = fmaf(wx, m1.y - m1.x, m1.x);
        float mm = fmaf(wy, u - t, t);
        float dd = mm - 0.5f;
        mAcc = fmaf(dd, dd, mAcc);
    }

    // --- reduce: wave shuffle, cross-wave via LDS ---
#pragma unroll
    for (int off = 32; off > 0; off >>= 1) {
        eAcc += __shfl_xor(eAcc, off);
        mAcc += __shfl_xor(mAcc, off);
    }
    const int wv = threadIdx.x >> 6;
    const int ln = threadIdx.x & 63;
    if (ln == 0) { redE[wv] = eAcc; redM[wv] = mAcc; }
    __syncthreads();

    if (threadIdx.x == 0) {
        float e = 0.f, m = 0.f;
#pragma unroll
        for (int w = 0; w < THREADS / 64; ++w) { e += redE[w]; m += redM[w]; }
        atomicAdd(&acc[0], (double)e);
        atomicAdd(&acc[1], (double)m);
        __threadfence();
        unsigned old = atomicAdd((unsigned*)&acc[2], 1u);
        if (old == (unsigned)(gridDim.x - 1)) {
            // last block: read back via atomic (coherent across XCDs), finalize
            double se = atomicAdd(&acc[0], 0.0);
            double sm = atomicAdd(&acc[1], 0.0);
            const double inv = 1.0 / (double)((long long)Bn * (long long)Nn);
            double edge_loss = 1.0 - se * inv;
            double mask_loss = sm * inv;
            out[0] = (float)(edge_loss + 2.0 * mask_loss);
        }
    }
}

extern "C" void kernel_launch(void* const* d_in, const int* in_sizes, int n_in,
                              void* d_out, int out_size, void* d_ws, size_t ws_size,
                              hipStream_t stream)
{
    const float* corners = (const float*)d_in[0];
    const float* edge    = (const float*)d_in[1];
    const float* mask    = (const float*)d_in[2];
    float* out  = (float*)d_out;
    double* acc = (double*)d_ws;

    hipMemsetAsync(acc, 0, 32, stream);   // 2 doubles + counter
    geo_kernel<<<Bn, THREADS, 0, stream>>>(corners, edge, mask, acc, out);
}